// Round 1
// baseline (123.163 us; speedup 1.0000x reference)
//
#include <hip/hip_runtime.h>
#include <stdint.h>

#define HASH_MASK 524287u        // HASHMAP_SIZE - 1 (power of two)
#define PRIME1 2654435761u
#define PRIME2 805459861u
#define RES 128.0f

__global__ __launch_bounds__(256) void hashgrid_fwd(
    const float* __restrict__ x,    // N*3 fp32
    const float* __restrict__ emb,  // H*2 fp32
    float* __restrict__ out,        // N*2 fp32
    int nthreads)                   // N/4
{
    int t = blockIdx.x * blockDim.x + threadIdx.x;
    if (t >= nthreads) return;

    // 4 points = 12 floats = 3 coalesced float4 loads
    const float4* xv = reinterpret_cast<const float4*>(x) + (size_t)t * 3;
    float4 a = xv[0];
    float4 b = xv[1];
    float4 c = xv[2];

    const float px[4][3] = {
        {a.x, a.y, a.z},
        {a.w, b.x, b.y},
        {b.z, b.w, c.x},
        {c.y, c.z, c.w},
    };

    const float2* __restrict__ embv = reinterpret_cast<const float2*>(emb);

    float2 res[4];

    #pragma unroll
    for (int p = 0; p < 4; ++p) {
        float fx = px[p][0] * RES;
        float fy = px[p][1] * RES;
        float fz = px[p][2] * RES;
        float flx = floorf(fx), fly = floorf(fy), flz = floorf(fz);
        int ix = (int)flx, iy = (int)fly, iz = (int)flz;
        float tx = fx - flx, ty = fy - fly, tz = fz - flz;

        // per-dim hash terms, lo (xi) and hi (xi+1)
        uint32_t h0a = (uint32_t)ix;                    // * 1
        uint32_t h0b = (uint32_t)(ix + 1);
        uint32_t h1a = (uint32_t)iy * PRIME1;
        uint32_t h1b = h1a + PRIME1;
        uint32_t h2a = (uint32_t)iz * PRIME2;
        uint32_t h2b = h2a + PRIME2;

        float wxa = 1.0f - tx, wxb = tx;
        float wya = 1.0f - ty, wyb = ty;
        float wza = 1.0f - tz, wzb = tz;

        // issue all 8 gathers first (independent), then accumulate
        uint32_t hid[8];
        float    wgt[8];
        #pragma unroll
        for (int n = 0; n < 8; ++n) {
            // BIN_MASK true when bit d of n is 0 -> lower index, weight (1-xf)
            uint32_t h = ((n & 1) ? h0b : h0a)
                       ^ ((n & 2) ? h1b : h1a)
                       ^ ((n & 4) ? h2b : h2a);
            hid[n] = h & HASH_MASK;
            wgt[n] = (((n & 1) ? wxb : wxa) * ((n & 2) ? wyb : wya))
                     * ((n & 4) ? wzb : wza);
        }

        float2 e[8];
        #pragma unroll
        for (int n = 0; n < 8; ++n) e[n] = embv[hid[n]];

        float s0 = 0.0f, s1 = 0.0f;
        #pragma unroll
        for (int n = 0; n < 8; ++n) {
            s0 = fmaf(e[n].x, wgt[n], s0);
            s1 = fmaf(e[n].y, wgt[n], s1);
        }
        res[p] = make_float2(s0, s1);
    }

    // 4 points * float2 = 2 coalesced float4 stores
    float4* ov = reinterpret_cast<float4*>(out) + (size_t)t * 2;
    ov[0] = make_float4(res[0].x, res[0].y, res[1].x, res[1].y);
    ov[1] = make_float4(res[2].x, res[2].y, res[3].x, res[3].y);
}

extern "C" void kernel_launch(void* const* d_in, const int* in_sizes, int n_in,
                              void* d_out, int out_size, void* d_ws, size_t ws_size,
                              hipStream_t stream) {
    const float* x   = (const float*)d_in[0];   // N*3
    const float* emb = (const float*)d_in[1];   // H*2
    float* out = (float*)d_out;                 // N*2

    int npts = in_sizes[0] / 3;                 // 4,000,000
    int nthreads = npts / 4;                    // 1,000,000 (N divisible by 4)
    int block = 256;
    int grid = (nthreads + block - 1) / block;  // 3907

    hashgrid_fwd<<<grid, block, 0, stream>>>(x, emb, out, nthreads);
}